// Round 4
// baseline (319.849 us; speedup 1.0000x reference)
//
#include <hip/hip_runtime.h>
#include <cstdint>
#include <cstddef>

#define N_NODES 50000
#define E_EDGES 800000
#define IN_F    128
#define PCOLS   512   // Pb cols: [0,96) Y0 | [96,192) Zpre | [192,288) Zblk | [288,480) Zpost | pad

typedef unsigned short ushortT;
typedef unsigned int   uintT;
typedef __attribute__((ext_vector_type(8))) short s8v;   // 8 bf16 (4 VGPR)
typedef __attribute__((ext_vector_type(4))) float f4v;   // 4 fp32 acc
typedef __attribute__((ext_vector_type(2))) float f2v;   // packed fp32 pair (v_pk_add_f32 target)

__device__ __forceinline__ float bflo(uintT u){ union{uintT i;float f;}c; c.i=u<<16; return c.f; }
__device__ __forceinline__ float bfhi(uintT u){ union{uintT i;float f;}c; c.i=u&0xFFFF0000u; return c.f; }
__device__ __forceinline__ ushortT f2bfu(float f){
    union{float f;uintT u;}c; c.f=f;
    uintT r = c.u + 0x7FFF + ((c.u>>16)&1);
    return (ushortT)(r>>16);
}
__device__ __forceinline__ uintT pack2(float a, float b){
    return (uintT)f2bfu(a) | ((uintT)f2bfu(b) << 16);
}

// ---------- prep1: pack weights + convert data + row_ptr + dummy-row zero ----------
// grid = 800000 threads exactly (N*IN_F/8)
__global__ void prep1(const float* __restrict__ A,
                      const float* __restrict__ Wp,  const float* __restrict__ bp,
                      const float* __restrict__ Tp,  const float* __restrict__ bTp,
                      const float* __restrict__ Tb,  const float* __restrict__ bTb,
                      const float* __restrict__ Tpo, const float* __restrict__ bTpo,
                      const float* __restrict__ Wpost,
                      const int* __restrict__ tgt,
                      ushortT* __restrict__ Wb, float* __restrict__ bcat,
                      float2* __restrict__ Wp2,
                      ushortT* __restrict__ Ab, int* __restrict__ row_ptr,
                      ushortT* __restrict__ Pb, ushortT* __restrict__ rb1,
                      ushortT* __restrict__ rb2)
{
    int gid = blockIdx.x * 256 + threadIdx.x;
    {
        size_t off = (size_t)gid * 8;
        float4 v0 = *(const float4*)(A + off);
        float4 v1 = *(const float4*)(A + off + 4);
        uint4 u;
        u.x = pack2(v0.x, v0.y); u.y = pack2(v0.z, v0.w);
        u.z = pack2(v1.x, v1.y); u.w = pack2(v1.z, v1.w);
        *(uint4*)(Ab + off) = u;
    }
    if (gid < IN_F * PCOLS) {
        int k = gid >> 9;
        int c = gid & 511;
        float v;
        if      (c < 96)  v = Wp [k*96  + c];
        else if (c < 192) v = Tp [k*96  + (c-96)];
        else if (c < 288) v = Tb [k*96  + (c-192)];
        else if (c < 480) v = Tpo[k*192 + (c-288)];
        else              v = 0.f;
        Wb[(size_t)c*IN_F + k] = f2bfu(v);
        if (k == 0) {
            float b;
            if      (c < 96)  b = bp  [c];
            else if (c < 192) b = bTp [c-96];
            else if (c < 288) b = bTb [c-192];
            else if (c < 480) b = bTpo[c-288];
            else              b = 0.f;
            bcat[c] = b;
        }
        if (gid < 3*16*64) {   // Wp2[(w*16+i2)*64+j] = (Wpost[w][2i2][j], Wpost[w][2i2+1][j])
            int w = gid >> 10, r = gid & 1023;
            int i2 = r >> 6, j = r & 63;
            Wp2[gid] = make_float2(Wpost[(w*32 + 2*i2)*64 + j],
                                   Wpost[(w*32 + 2*i2 + 1)*64 + j]);
        }
    }
    if (gid < 96) {   // dummy gather row (node N) = 0 in every gather source
        Pb [(size_t)N_NODES*PCOLS + gid] = 0;
        rb1[(size_t)N_NODES*96   + gid] = 0;
        rb2[(size_t)N_NODES*96   + gid] = 0;
    }
    if (gid <= N_NODES) {
        int lo = 0, hi = E_EDGES;
        while (lo < hi) {
            int mid = (lo + hi) >> 1;
            if (tgt[mid] < gid) lo = mid + 1; else hi = mid;
        }
        row_ptr[gid] = lo;
    }
}

// ---------- MFMA GEMM: Pb[M,512] = bf16(Ab[M,128] @ Wb^T + bcat) ----------
// B tile (128 cols x K=128) staged ONCE in LDS; A fragments load direct from global.
// Epilogue stages bf16 C through the same LDS buffer, coalesced uint4 writes.
// XCD-swizzled grid: 8 XCDs x 49 row-bands x 4 column-siblings.
__global__ __launch_bounds__(256, 4) void gemm_mfma(const ushortT* __restrict__ Ab,
                                                    const ushortT* __restrict__ Wb,
                                                    const float* __restrict__ bcat,
                                                    ushortT* __restrict__ Pb, int M)
{
    __shared__ ushortT Bsl[128][136];   // 34816 B; B tile [n][k], reused as C staging
    int tid = threadIdx.x;
    int i = blockIdx.x;                  // 1568 = 8 * 49 * 4
    int xcd = i & 7, j = i >> 3;         // j in [0,196)
    int nb = (j & 3) * 128;              // column block
    int mb = (xcd * 49 + (j >> 2)) * 128;// row band 0..391 (tail bands OOB-guarded)
    int wv = tid >> 6, lane = tid & 63;
    int wm = wv >> 1, wn = wv & 1;
    int cl = lane & 15, q = lane >> 4;

    // stage whole B tile (128 cols x 128 k) once
    #pragma unroll
    for (int r = 0; r < 8; ++r) {
        int idx = tid + 256*r;
        int row = idx >> 4, qq = idx & 15;
        uint4 v = *(const uint4*)(Wb + (size_t)(nb+row)*IN_F + qq*8);
        *(uint4*)(&Bsl[row][qq*8]) = v;
    }
    __syncthreads();

    f4v acc[4][4];
    #pragma unroll
    for (int a = 0; a < 4; ++a)
        #pragma unroll
        for (int b = 0; b < 4; ++b) acc[a][b] = (f4v)0.f;

    int gmBase = mb + wm*64;
    #pragma unroll
    for (int ks = 0; ks < 4; ++ks) {
        int ko = ks*32 + q*8;
        s8v af[4], bf[4];
        #pragma unroll
        for (int mt = 0; mt < 4; ++mt) {
            int gm = gmBase + mt*16 + cl;
            uint4 va = make_uint4(0,0,0,0);
            if (gm < M) va = *(const uint4*)(Ab + (size_t)gm*IN_F + ko);
            af[mt] = *(s8v*)&va;
        }
        #pragma unroll
        for (int nt = 0; nt < 4; ++nt)
            bf[nt] = *(const s8v*)(&Bsl[wn*64 + nt*16 + cl][ko]);
        #pragma unroll
        for (int mt = 0; mt < 4; ++mt)
            #pragma unroll
            for (int nt = 0; nt < 4; ++nt)
                acc[mt][nt] = __builtin_amdgcn_mfma_f32_16x16x32_bf16(af[mt], bf[nt], acc[mt][nt], 0, 0, 0);
    }

    __syncthreads();   // all waves done reading Bsl -> reuse as C staging

    // bias + pack bf16 into LDS [row-in-tile][col-in-tile]
    #pragma unroll
    for (int nt = 0; nt < 4; ++nt) {
        int cn = wn*64 + nt*16 + cl;
        float bv = bcat[nb + cn];
        #pragma unroll
        for (int mt = 0; mt < 4; ++mt) {
            int rm0 = wm*64 + mt*16 + q*4;
            #pragma unroll
            for (int r = 0; r < 4; ++r)
                Bsl[rm0 + r][cn] = f2bfu(acc[mt][nt][r] + bv);
        }
    }
    __syncthreads();

    // coalesced write-out: 8 passes, each 16 rows x 256 B
    #pragma unroll
    for (int p = 0; p < 8; ++p) {
        int idx = tid + 256*p;
        int row = idx >> 4, sg = idx & 15;
        int gm = mb + row;
        if (gm < M) {
            uint4 v = *(const uint4*)(&Bsl[row][sg*8]);
            *(uint4*)(Pb + (size_t)gm*PCOLS + nb + sg*8) = v;
        }
    }
}

// ===== dwordx2 paired-row gather =====
// Slot s loads TWO edge rows: lanes 0-23 -> edge 2s (8B = feats 4lq..4lq+3),
// lanes 24-47 -> edge 2s+1, lanes 48-63 duplicate lane 0 (coalesced, discarded).
// One 12-slot window = 24 edges = ONE memory round trip for 97.8% of nodes.
// Requires in scope: lane, lq, hb (bpermute byte sel 0/4), inner8, src.
#define ISSUE_W2(Xb, sv, bs, u)                                                   \
    _Pragma("unroll")                                                             \
    for (int s_ = 0; s_ < 12; ++s_) {                                             \
        int vrow_ = __builtin_amdgcn_ds_bpermute(hb + ((bs) + s_)*8, sv);         \
        u[s_] = *(const uint2*)((const char*)(Xb) + (uintT)(vrow_ + inner8));     \
    }
#define SUM_W2(u, p0, p1, q0, q1)                                                 \
    _Pragma("unroll")                                                             \
    for (int s_ = 0; s_ < 12; ++s_) {                                             \
        f2v a_; a_.x = bflo(u[s_].x); a_.y = bfhi(u[s_].x);                       \
        f2v b_; b_.x = bflo(u[s_].y); b_.y = bfhi(u[s_].y);                       \
        if (s_ & 1) { p1 += a_; q1 += b_; } else { p0 += a_; q0 += b_; }          \
    }
// Full gather: sx,sy = neighbor-sum at feats (2*lane, 2*lane+1), valid for lane<48.
// Final 8-shuffle transform converts 24-lane x 4-feat sums to the 48-lane x 2 layout.
#define GATHER2(Xb, lo, deg, sv, STRB, sx, sy)                                    \
    float sx, sy;                                                                 \
    {                                                                             \
        f2v p0={0.f,0.f}, p1={0.f,0.f}, q0={0.f,0.f}, q1={0.f,0.f};               \
        uint2 u[12];                                                              \
        ISSUE_W2(Xb, sv, 0, u)                                                    \
        SUM_W2(u, p0, p1, q0, q1)                                                 \
        if (deg > 24) {                                                           \
            ISSUE_W2(Xb, sv, 12, u)                                               \
            SUM_W2(u, p0, p1, q0, q1)                                             \
        }                                                                         \
        if (deg > 48) {                                                           \
            _Pragma("unroll 1")                                                   \
            for (int j_ = lo + 48; j_ < lo + deg; ++j_) {                         \
                int off_ = src[j_] * (STRB);                                      \
                uint2 t_ = *(const uint2*)((const char*)(Xb) + (uintT)(off_ + inner8)); \
                if (lane < 24) {                                                  \
                    f2v a_; a_.x = bflo(t_.x); a_.y = bfhi(t_.x);                 \
                    f2v b_; b_.x = bflo(t_.y); b_.y = bfhi(t_.y);                 \
                    p0 += a_; q0 += b_;                                           \
                }                                                                 \
            }                                                                     \
        }                                                                         \
        f2v pt_ = p0 + p1, qt_ = q0 + q1;                                         \
        int le_ = lane >> 1;                                                      \
        float Ex_ = __shfl(pt_.x, le_),    Ey_ = __shfl(pt_.y, le_);              \
        float Fx_ = __shfl(qt_.x, le_),    Fy_ = __shfl(qt_.y, le_);              \
        float Gx_ = __shfl(pt_.x, le_+24), Gy_ = __shfl(pt_.y, le_+24);           \
        float Hx_ = __shfl(qt_.x, le_+24), Hy_ = __shfl(qt_.y, le_+24);           \
        bool od_ = (lane & 1);                                                    \
        sx = (od_ ? Fx_ : Ex_) + (od_ ? Hx_ : Gx_);                               \
        sy = (od_ ? Fy_ : Ey_) + (od_ ? Hy_ : Gy_);                               \
    }

// per-lane gather slot from raw src: lane<deg ? src[lo+lane] : dummy row N
#define MAKE_SV(lo, deg, lane, STRB, sv)                                          \
    int sv;                                                                       \
    {                                                                             \
        int e_ = (lo) + (lane);                                                   \
        if (e_ > E_EDGES - 1) e_ = E_EDGES - 1;                                   \
        int sn_ = src[e_];                                                        \
        sv = ((lane) < (deg) ? sn_ : N_NODES) * (STRB);                           \
    }

#define LANE_GEO                                                                  \
    int lane = threadIdx.x & 63;                                                  \
    int pL = lane < 48 ? lane : 0;                                                \
    int lq = lane < 24 ? lane : (lane < 48 ? lane - 24 : 0);                      \
    int hb = (lane >= 24 && lane < 48) ? 4 : 0;                                   \
    int inner8 = lq * 8;

// ---------- layer 1: rb1 = bf16(relu(Lap(Y0) + Zpre)), wave per node ----------
__global__ __launch_bounds__(256, 8) void lap1(
    const ushortT* __restrict__ Pb,
    const int* __restrict__ src, const int* __restrict__ row_ptr,
    ushortT* __restrict__ rb1)
{
    LANE_GEO
    int t  = __builtin_amdgcn_readfirstlane((blockIdx.x << 2) + (threadIdx.x >> 6));
    int lo = __builtin_amdgcn_readfirstlane(row_ptr[t]);
    int deg = __builtin_amdgcn_readfirstlane(row_ptr[t+1]) - lo;
    MAKE_SV(lo, deg, lane, 2*PCOLS, sv)                    // Pb row = 1024 B
    uintT ux = *(const uintT*)(Pb + (size_t)t*PCOLS + 2*pL);        // Y0 cols 2pL,2pL+1
    uintT zu = *(const uintT*)(Pb + (size_t)t*PCOLS + 96 + 2*pL);   // Zpre

    GATHER2(Pb, lo, deg, sv, 2*PCOLS, sx, sy)

    float inv = deg > 0 ? 1.f/(float)deg : 0.f;
    float mf  = deg > 0 ? 1.f : 0.f;
    if (lane < 48) {
        float ox = fmaxf(mf*bflo(ux) - sx*inv + bflo(zu), 0.f);
        float oy = fmaxf(mf*bfhi(ux) - sy*inv + bfhi(zu), 0.f);
        *(uintT*)(rb1 + (size_t)t*96 + 2*pL) = pack2(ox, oy);
    }
}

// ---------- layer 2: rb2 = bf16(relu(Lap(rb1)@W_blk + Zblk)) ----------
// persistent: 3125 blocks x 4 iters; weights staged once per block
__global__ __launch_bounds__(256, 8) void lap2(
    const ushortT* __restrict__ Xb,    // rb1 [N+1,96]
    const ushortT* __restrict__ Pb,    // Zblk = cols 192..287
    const int* __restrict__ src, const int* __restrict__ row_ptr,
    const float* __restrict__ Wblk,    // [3][32][32] flat
    ushortT* __restrict__ rb2)
{
    __shared__ float wS[3*32*32];
    for (int i = threadIdx.x; i < 3072; i += 256) wS[i] = Wblk[i];
    __syncthreads();

    LANE_GEO
    int wvw  = threadIdx.x >> 6;
    int w  = pL >> 4;            // group (uniform per 16-lane slab)
    int jj = pL & 15;            // out pair index within group
    const float2* wc = ((const float2*)wS) + (w*512 + jj);   // &W[w][0][2jj]

    #pragma unroll 1
    for (int it = 0; it < 4; ++it) {
        int t  = __builtin_amdgcn_readfirstlane(blockIdx.x*16 + it*4 + wvw);
        int lo = __builtin_amdgcn_readfirstlane(row_ptr[t]);
        int deg = __builtin_amdgcn_readfirstlane(row_ptr[t+1]) - lo;
        MAKE_SV(lo, deg, lane, 192, sv)
        uintT ux = *(const uintT*)(Xb + (size_t)t*96 + 2*pL);
        uintT zu = *(const uintT*)(Pb + (size_t)t*PCOLS + 192 + 2*pL);

        GATHER2(Xb, lo, deg, sv, 192, sx, sy)

        float inv = deg > 0 ? 1.f/(float)deg : 0.f;
        float mf  = deg > 0 ? 1.f : 0.f;
        float Lx = mf*bflo(ux) - sx*inv;    // Lap feat 2pL
        float Ly = mf*bfhi(ux) - sy*inv;    // Lap feat 2pL+1

        // conv (no bias): out channels (2pL, 2pL+1), inputs = group-w feats via shfl
        float accx = 0.f, accy = 0.f;
        #pragma unroll
        for (int d = 0; d < 16; ++d) {
            int sl = w*16 + d;
            float ax = __shfl(Lx, sl);      // feat 32w+2d
            float ay = __shfl(Ly, sl);      // feat 32w+2d+1
            float2 wa = wc[(2*d)*16];       // W[w][2d][2jj..2jj+1]
            float2 wb = wc[(2*d+1)*16];
            accx = fmaf(ax, wa.x, accx); accx = fmaf(ay, wb.x, accx);
            accy = fmaf(ax, wa.y, accy); accy = fmaf(ay, wb.y, accy);
        }
        if (lane < 48) {
            float ox = fmaxf(accx + bflo(zu), 0.f);
            float oy = fmaxf(accy + bfhi(zu), 0.f);
            *(uintT*)(rb2 + (size_t)t*96 + 2*pL) = pack2(ox, oy);
        }
    }
}

// ---------- layer 3: out = widthmean(relu(Lap(rb2)@W_post + Zpost)) ----------
// persistent: 3125 blocks x 4 iters; weights staged once per block
__global__ __launch_bounds__(256, 8) void lap3(
    const ushortT* __restrict__ Xb,    // rb2 [N+1,96]
    const ushortT* __restrict__ Pb,    // Zpost = cols 288..479
    const int* __restrict__ src, const int* __restrict__ row_ptr,
    const float2* __restrict__ Wp2,    // [3][16][64] float2
    float* __restrict__ out)
{
    __shared__ float2 wS[3*16*64];
    __shared__ float  sm[4][96];       // per-wave activation slab (wave DS in-order)
    for (int i = threadIdx.x; i < 3072; i += 256) wS[i] = Wp2[i];
    __syncthreads();

    LANE_GEO
    int wvw  = threadIdx.x >> 6;
    const float2* wl = wS + lane;      // step 64 float2 per (w,i2)

    #pragma unroll 1
    for (int it = 0; it < 4; ++it) {
        int t  = __builtin_amdgcn_readfirstlane(blockIdx.x*16 + it*4 + wvw);
        int lo = __builtin_amdgcn_readfirstlane(row_ptr[t]);
        int deg = __builtin_amdgcn_readfirstlane(row_ptr[t+1]) - lo;
        MAKE_SV(lo, deg, lane, 192, sv)
        uintT ux = *(const uintT*)(Xb + (size_t)t*96 + 2*pL);
        float z0 = bflo((uintT)Pb[(size_t)t*PCOLS + 288 + lane]);   // ch lane
        float z1 = bflo((uintT)Pb[(size_t)t*PCOLS + 352 + lane]);   // ch 64+lane
        float z2 = bflo((uintT)Pb[(size_t)t*PCOLS + 416 + lane]);   // ch 128+lane

        GATHER2(Xb, lo, deg, sv, 192, sx, sy)

        float inv = deg > 0 ? 1.f/(float)deg : 0.f;
        float mf  = deg > 0 ? 1.f : 0.f;
        float Lx = mf*bflo(ux) - sx*inv;
        float Ly = mf*bfhi(ux) - sy*inv;

        // broadcast activations through per-wave LDS (uniform-address ds_read = broadcast)
        if (lane < 48) {
            sm[wvw][2*pL]     = Lx;
            sm[wvw][2*pL + 1] = Ly;
        }
        __builtin_amdgcn_wave_barrier();   // pin compiler order; wave DS ops are HW-in-order

        // conv: lane computes channels {L, 64+L, 128+L}
        float a0 = 0.f, a1 = 0.f, a2 = 0.f;
        #pragma unroll
        for (int w2 = 0; w2 < 3; ++w2) {
            float acc = 0.f;
            #pragma unroll
            for (int i2 = 0; i2 < 16; ++i2) {
                float2 iv = *(const float2*)(&sm[wvw][w2*32 + 2*i2]);   // broadcast read
                float2 p  = wl[(w2*16 + i2)*64];
                acc = fmaf(iv.x, p.x, acc);
                acc = fmaf(iv.y, p.y, acc);
            }
            if (w2 == 0) a0 = acc; else if (w2 == 1) a1 = acc; else a2 = acc;
        }
        __builtin_amdgcn_wave_barrier();   // reads done before next iter's sm writes

        float o0 = fmaxf(a0 + z0, 0.f);   // channel lane
        float o1 = fmaxf(a1 + z1, 0.f);   // channel 64+lane
        float o2 = fmaxf(a2 + z2, 0.f);   // channel 128+lane
        // width-mean: final[f] = (v(3f)+v(3f+1)+v(3f+2))/3, v(c) = o_{c>>6} @ lane c&63
        float r = 0.f;
        #pragma unroll
        for (int q = 0; q < 3; ++q) {
            int c = 3*lane + q;
            int sl = c & 63, wsel = c >> 6;
            float v0 = __shfl(o0, sl);
            float v1 = __shfl(o1, sl);
            float v2 = __shfl(o2, sl);
            r += (wsel == 0) ? v0 : ((wsel == 1) ? v1 : v2);
        }
        out[(size_t)t*64 + lane] = r * (1.0f/3.0f);
    }
}

extern "C" void kernel_launch(void* const* d_in, const int* in_sizes, int n_in,
                              void* d_out, int out_size, void* d_ws, size_t ws_size,
                              hipStream_t stream)
{
    const float* data    = (const float*)d_in[0];
    const int*   src     = (const int*)  d_in[1];
    const int*   tgt     = (const int*)  d_in[2];
    const float* W_pre   = (const float*)d_in[3];
    const float* b_pre   = (const float*)d_in[4];
    const float* T_pre   = (const float*)d_in[5];
    const float* bT_pre  = (const float*)d_in[6];
    const float* W_blk   = (const float*)d_in[7];
    const float* b_blk   = (const float*)d_in[8];   // cancels under Lap — unused
    const float* T_blk   = (const float*)d_in[9];
    const float* bT_blk  = (const float*)d_in[10];
    const float* W_post  = (const float*)d_in[11];
    const float* b_post  = (const float*)d_in[12];  // cancels under Lap — unused
    const float* T_post  = (const float*)d_in[13];
    const float* bT_post = (const float*)d_in[14];
    float* out = (float*)d_out;

    float*   ws      = (float*)d_ws;
    float*   bcat    = ws;                                   // 512 f32
    float2*  Wp2     = (float2*)(bcat + 512);                // 3*16*64 float2
    int*     row_ptr = (int*)(Wp2 + 3*16*64);                // 50008
    ushortT* Pb      = (ushortT*)(row_ptr + 50008);          // (N+1)*512 bf16
    ushortT* rb1     = Pb  + (size_t)(N_NODES+1) * PCOLS;    // (N+1)*96 bf16
    ushortT* rb2     = rb1 + (size_t)(N_NODES+1) * 96;       // (N+1)*96 bf16
    ushortT* Ab      = rb2 + (size_t)(N_NODES+1) * 96;       // N*128 bf16
    ushortT* Wb      = Ab  + (size_t)N_NODES * IN_F;         // 512*128 bf16

    prep1<<<(N_NODES*IN_F/8)/256, 256, 0, stream>>>(
        data, W_pre, b_pre, T_pre, bT_pre, T_blk, bT_blk, T_post, bT_post,
        W_post, tgt, Wb, bcat, Wp2, Ab, row_ptr, Pb, rb1, rb2);

    gemm_mfma<<<1568, 256, 0, stream>>>(Ab, Wb, bcat, Pb, N_NODES);

    lap1<<<N_NODES/4, 256, 0, stream>>>(Pb, src, row_ptr, rb1);
    lap2<<<N_NODES/16, 256, 0, stream>>>(rb1, Pb, src, row_ptr, W_blk, rb2);
    lap3<<<N_NODES/16, 256, 0, stream>>>(rb2, Pb, src, row_ptr, Wp2, out);
}

// Round 5
// 274.758 us; speedup vs baseline: 1.1641x; 1.1641x over previous
//
#include <hip/hip_runtime.h>
#include <cstdint>
#include <cstddef>

#define N_NODES 50000
#define E_EDGES 800000
#define IN_F    128
#define PCOLS   512   // Pb cols: [0,96) Y0 | [96,192) Zpre | [192,288) Zblk | [288,480) Zpost | pad

typedef unsigned short ushortT;
typedef unsigned int   uintT;
typedef __attribute__((ext_vector_type(8))) short s8v;   // 8 bf16 (4 VGPR)
typedef __attribute__((ext_vector_type(4))) float f4v;   // 4 fp32 acc
typedef __attribute__((ext_vector_type(2))) float f2v;   // packed fp32 pair (v_pk_add_f32 target)

__device__ __forceinline__ float bflo(uintT u){ union{uintT i;float f;}c; c.i=u<<16; return c.f; }
__device__ __forceinline__ float bfhi(uintT u){ union{uintT i;float f;}c; c.i=u&0xFFFF0000u; return c.f; }
__device__ __forceinline__ ushortT f2bfu(float f){
    union{float f;uintT u;}c; c.f=f;
    uintT r = c.u + 0x7FFF + ((c.u>>16)&1);
    return (ushortT)(r>>16);
}
__device__ __forceinline__ uintT pack2(float a, float b){
    return (uintT)f2bfu(a) | ((uintT)f2bfu(b) << 16);
}

// ---------- prep1: pack weights + convert data + row_ptr + dummy-row zero ----------
// grid = 800000 threads exactly (N*IN_F/8)
__global__ void prep1(const float* __restrict__ A,
                      const float* __restrict__ Wp,  const float* __restrict__ bp,
                      const float* __restrict__ Tp,  const float* __restrict__ bTp,
                      const float* __restrict__ Tb,  const float* __restrict__ bTb,
                      const float* __restrict__ Tpo, const float* __restrict__ bTpo,
                      const float* __restrict__ Wpost,
                      const int* __restrict__ tgt,
                      ushortT* __restrict__ Wb, float* __restrict__ bcat,
                      float2* __restrict__ Wp2,
                      ushortT* __restrict__ Ab, int* __restrict__ row_ptr,
                      ushortT* __restrict__ Pb, ushortT* __restrict__ rb1,
                      ushortT* __restrict__ rb2)
{
    int gid = blockIdx.x * 256 + threadIdx.x;
    {
        size_t off = (size_t)gid * 8;
        float4 v0 = *(const float4*)(A + off);
        float4 v1 = *(const float4*)(A + off + 4);
        uint4 u;
        u.x = pack2(v0.x, v0.y); u.y = pack2(v0.z, v0.w);
        u.z = pack2(v1.x, v1.y); u.w = pack2(v1.z, v1.w);
        *(uint4*)(Ab + off) = u;
    }
    if (gid < IN_F * PCOLS) {
        int k = gid >> 9;
        int c = gid & 511;
        float v;
        if      (c < 96)  v = Wp [k*96  + c];
        else if (c < 192) v = Tp [k*96  + (c-96)];
        else if (c < 288) v = Tb [k*96  + (c-192)];
        else if (c < 480) v = Tpo[k*192 + (c-288)];
        else              v = 0.f;
        Wb[(size_t)c*IN_F + k] = f2bfu(v);
        if (k == 0) {
            float b;
            if      (c < 96)  b = bp  [c];
            else if (c < 192) b = bTp [c-96];
            else if (c < 288) b = bTb [c-192];
            else if (c < 480) b = bTpo[c-288];
            else              b = 0.f;
            bcat[c] = b;
        }
        if (gid < 3*16*64) {   // Wp2[(w*16+i2)*64+j] = (Wpost[w][2i2][j], Wpost[w][2i2+1][j])
            int w = gid >> 10, r = gid & 1023;
            int i2 = r >> 6, j = r & 63;
            Wp2[gid] = make_float2(Wpost[(w*32 + 2*i2)*64 + j],
                                   Wpost[(w*32 + 2*i2 + 1)*64 + j]);
        }
    }
    if (gid < 96) {   // dummy gather row (node N) = 0 in every gather source
        Pb [(size_t)N_NODES*PCOLS + gid] = 0;
        rb1[(size_t)N_NODES*96   + gid] = 0;
        rb2[(size_t)N_NODES*96   + gid] = 0;
    }
    if (gid <= N_NODES) {
        int lo = 0, hi = E_EDGES;
        while (lo < hi) {
            int mid = (lo + hi) >> 1;
            if (tgt[mid] < gid) lo = mid + 1; else hi = mid;
        }
        row_ptr[gid] = lo;
    }
}

// ---------- MFMA GEMM: Pb[M,512] = bf16(Ab[M,128] @ Wb^T + bcat) ----------
// B tile (128 cols x K=128) staged ONCE in LDS; A fragments load direct from global.
// Epilogue stages bf16 C through the same LDS buffer, coalesced uint4 writes.
// XCD-swizzled grid: 8 XCDs x 49 row-bands x 4 column-siblings.
__global__ __launch_bounds__(256, 4) void gemm_mfma(const ushortT* __restrict__ Ab,
                                                    const ushortT* __restrict__ Wb,
                                                    const float* __restrict__ bcat,
                                                    ushortT* __restrict__ Pb, int M)
{
    __shared__ ushortT Bsl[128][136];   // 34816 B; B tile [n][k], reused as C staging
    int tid = threadIdx.x;
    int i = blockIdx.x;                  // 1568 = 8 * 49 * 4
    int xcd = i & 7, j = i >> 3;         // j in [0,196)
    int nb = (j & 3) * 128;              // column block
    int mb = (xcd * 49 + (j >> 2)) * 128;// row band 0..391 (tail bands OOB-guarded)
    int wv = tid >> 6, lane = tid & 63;
    int wm = wv >> 1, wn = wv & 1;
    int cl = lane & 15, q = lane >> 4;

    // stage whole B tile (128 cols x 128 k) once
    #pragma unroll
    for (int r = 0; r < 8; ++r) {
        int idx = tid + 256*r;
        int row = idx >> 4, qq = idx & 15;
        uint4 v = *(const uint4*)(Wb + (size_t)(nb+row)*IN_F + qq*8);
        *(uint4*)(&Bsl[row][qq*8]) = v;
    }
    __syncthreads();

    f4v acc[4][4];
    #pragma unroll
    for (int a = 0; a < 4; ++a)
        #pragma unroll
        for (int b = 0; b < 4; ++b) acc[a][b] = (f4v)0.f;

    int gmBase = mb + wm*64;
    #pragma unroll
    for (int ks = 0; ks < 4; ++ks) {
        int ko = ks*32 + q*8;
        s8v af[4], bf[4];
        #pragma unroll
        for (int mt = 0; mt < 4; ++mt) {
            int gm = gmBase + mt*16 + cl;
            uint4 va = make_uint4(0,0,0,0);
            if (gm < M) va = *(const uint4*)(Ab + (size_t)gm*IN_F + ko);
            af[mt] = *(s8v*)&va;
        }
        #pragma unroll
        for (int nt = 0; nt < 4; ++nt)
            bf[nt] = *(const s8v*)(&Bsl[wn*64 + nt*16 + cl][ko]);
        #pragma unroll
        for (int mt = 0; mt < 4; ++mt)
            #pragma unroll
            for (int nt = 0; nt < 4; ++nt)
                acc[mt][nt] = __builtin_amdgcn_mfma_f32_16x16x32_bf16(af[mt], bf[nt], acc[mt][nt], 0, 0, 0);
    }

    __syncthreads();   // all waves done reading Bsl -> reuse as C staging

    // bias + pack bf16 into LDS [row-in-tile][col-in-tile]
    #pragma unroll
    for (int nt = 0; nt < 4; ++nt) {
        int cn = wn*64 + nt*16 + cl;
        float bv = bcat[nb + cn];
        #pragma unroll
        for (int mt = 0; mt < 4; ++mt) {
            int rm0 = wm*64 + mt*16 + q*4;
            #pragma unroll
            for (int r = 0; r < 4; ++r)
                Bsl[rm0 + r][cn] = f2bfu(acc[mt][nt][r] + bv);
        }
    }
    __syncthreads();

    // coalesced write-out: 8 passes, each 16 rows x 256 B
    #pragma unroll
    for (int p = 0; p < 8; ++p) {
        int idx = tid + 256*p;
        int row = idx >> 4, sg = idx & 15;
        int gm = mb + row;
        if (gm < M) {
            uint4 v = *(const uint4*)(&Bsl[row][sg*8]);
            *(uint4*)(Pb + (size_t)gm*PCOLS + nb + sg*8) = v;
        }
    }
}

// ===== gather core: 24-deep first window (one round trip for 97.7% of nodes) =====
// sv holds PRE-SCALED byte offsets (row*STRB). (Xb + off) is wave-uniform -> saddr form;
// 4*pL is the per-lane constant voffset. STRB = gather-source row stride in BYTES.
// Windows: [0,24) | [24,48) | [48,64) | serial tail. u[24] = 24 VGPR of window state;
// total kernel VGPR must stay <= 64 (occupancy cliff) — no launch-bounds pressure.
#define GATHER96(Xb, lo, deg, sv, pL, STRB, sx, sy)                               \
    float sx, sy;                                                                 \
    {                                                                             \
        f2v c0={0.f,0.f}, c1={0.f,0.f}, c2={0.f,0.f}, c3={0.f,0.f};               \
        uintT u[24];                                                              \
        _Pragma("unroll")                                                         \
        for (int kk = 0; kk < 24; ++kk) {                                         \
            int off = __builtin_amdgcn_readlane(sv, kk);                          \
            u[kk] = *(const uintT*)((const char*)(Xb) + off + 4*(pL));            \
        }                                                                         \
        _Pragma("unroll")                                                         \
        for (int kk = 0; kk < 24; ++kk) {                                         \
            f2v v_; v_.x = bflo(u[kk]); v_.y = bfhi(u[kk]);                       \
            switch (kk & 3) {                                                     \
                case 0: c0 += v_; break;                                          \
                case 1: c1 += v_; break;                                          \
                case 2: c2 += v_; break;                                          \
                default:c3 += v_; break;                                          \
            }                                                                     \
        }                                                                         \
        if (deg > 24) {                                                           \
            _Pragma("unroll")                                                     \
            for (int kk = 0; kk < 24; ++kk) {                                     \
                int off = __builtin_amdgcn_readlane(sv, 24 + kk);                 \
                u[kk] = *(const uintT*)((const char*)(Xb) + off + 4*(pL));        \
            }                                                                     \
            _Pragma("unroll")                                                     \
            for (int kk = 0; kk < 24; ++kk) {                                     \
                f2v v_; v_.x = bflo(u[kk]); v_.y = bfhi(u[kk]);                   \
                switch (kk & 3) {                                                 \
                    case 0: c0 += v_; break;                                      \
                    case 1: c1 += v_; break;                                      \
                    case 2: c2 += v_; break;                                      \
                    default:c3 += v_; break;                                      \
                }                                                                 \
            }                                                                     \
        }                                                                         \
        if (deg > 48) {                                                           \
            _Pragma("unroll")                                                     \
            for (int kk = 0; kk < 16; ++kk) {                                     \
                int off = __builtin_amdgcn_readlane(sv, 48 + kk);                 \
                u[kk] = *(const uintT*)((const char*)(Xb) + off + 4*(pL));        \
            }                                                                     \
            _Pragma("unroll")                                                     \
            for (int kk = 0; kk < 16; ++kk) {                                     \
                f2v v_; v_.x = bflo(u[kk]); v_.y = bfhi(u[kk]);                   \
                switch (kk & 3) {                                                 \
                    case 0: c0 += v_; break;                                      \
                    case 1: c1 += v_; break;                                      \
                    case 2: c2 += v_; break;                                      \
                    default:c3 += v_; break;                                      \
                }                                                                 \
            }                                                                     \
        }                                                                         \
        if (deg > 64) {                                                           \
            _Pragma("unroll 1")                                                   \
            for (int j_ = lo + 64; j_ < lo + deg; ++j_) {                         \
                int off = src[j_] * (STRB);                                       \
                uintT u0 = *(const uintT*)((const char*)(Xb) + off + 4*(pL));     \
                f2v v_; v_.x = bflo(u0); v_.y = bfhi(u0);                         \
                c0 += v_;                                                         \
            }                                                                     \
        }                                                                         \
        f2v cs_ = (c0 + c1) + (c2 + c3);                                          \
        sx = cs_.x; sy = cs_.y;                                                   \
    }

// per-lane gather slot from raw src: lane<deg ? src[lo+lane] : dummy row N
#define MAKE_SV(lo, deg, lane, STRB, sv)                                          \
    int sv;                                                                       \
    {                                                                             \
        int e_ = (lo) + (lane);                                                   \
        if (e_ > E_EDGES - 1) e_ = E_EDGES - 1;                                   \
        int sn_ = src[e_];                                                        \
        sv = ((lane) < (deg) ? sn_ : N_NODES) * (STRB);                           \
    }

// ---------- layer 1: rb1 = bf16(relu(Lap(Y0) + Zpre)), wave per node ----------
// own-x, Z and the gather all come from bf16 Pb (row stride 1024 B, cols 0..95 = Y0)
__global__ __launch_bounds__(256) void lap1(
    const ushortT* __restrict__ Pb,
    const int* __restrict__ src, const int* __restrict__ row_ptr,
    ushortT* __restrict__ rb1)
{
    int lane = threadIdx.x & 63;
    int t  = __builtin_amdgcn_readfirstlane((blockIdx.x << 2) + (threadIdx.x >> 6));
    int lo = __builtin_amdgcn_readfirstlane(row_ptr[t]);
    int deg = __builtin_amdgcn_readfirstlane(row_ptr[t+1]) - lo;
    int pL = lane < 48 ? lane : 0;
    MAKE_SV(lo, deg, lane, 2*PCOLS, sv)                    // Pb row = 1024 B
    uintT ux = *(const uintT*)(Pb + (size_t)t*PCOLS + 2*pL);        // Y0 cols 2pL,2pL+1
    uintT zu = *(const uintT*)(Pb + (size_t)t*PCOLS + 96 + 2*pL);   // Zpre

    GATHER96(Pb, lo, deg, sv, pL, 2*PCOLS, sx, sy)

    float inv = deg > 0 ? 1.f/(float)deg : 0.f;
    float mf  = deg > 0 ? 1.f : 0.f;
    if (lane < 48) {
        float ox = fmaxf(mf*bflo(ux) - sx*inv + bflo(zu), 0.f);
        float oy = fmaxf(mf*bfhi(ux) - sy*inv + bfhi(zu), 0.f);
        *(uintT*)(rb1 + (size_t)t*96 + 2*pL) = pack2(ox, oy);
    }
}

// ---------- layer 2: rb2 = bf16(relu(Lap(rb1)@W_blk + Zblk)) ----------
// persistent: 3125 blocks x 4 iters; weights staged once per block
__global__ __launch_bounds__(256) void lap2(
    const ushortT* __restrict__ Xb,    // rb1 [N+1,96]
    const ushortT* __restrict__ Pb,    // Zblk = cols 192..287
    const int* __restrict__ src, const int* __restrict__ row_ptr,
    const float* __restrict__ Wblk,    // [3][32][32] flat
    ushortT* __restrict__ rb2)
{
    __shared__ float wS[3*32*32];
    for (int i = threadIdx.x; i < 3072; i += 256) wS[i] = Wblk[i];
    __syncthreads();

    int lane = threadIdx.x & 63;
    int wvw  = threadIdx.x >> 6;
    int pL = lane < 48 ? lane : 0;
    int w  = pL >> 4;            // group (uniform per 16-lane slab)
    int jj = pL & 15;            // out pair index within group
    const float2* wc = ((const float2*)wS) + (w*512 + jj);   // &W[w][0][2jj]

    #pragma unroll 1
    for (int it = 0; it < 4; ++it) {
        int t  = __builtin_amdgcn_readfirstlane(blockIdx.x*16 + it*4 + wvw);
        int lo = __builtin_amdgcn_readfirstlane(row_ptr[t]);
        int deg = __builtin_amdgcn_readfirstlane(row_ptr[t+1]) - lo;
        MAKE_SV(lo, deg, lane, 192, sv)
        uintT ux = *(const uintT*)(Xb + (size_t)t*96 + 2*pL);
        uintT zu = *(const uintT*)(Pb + (size_t)t*PCOLS + 192 + 2*pL);

        GATHER96(Xb, lo, deg, sv, pL, 192, sx, sy)

        float inv = deg > 0 ? 1.f/(float)deg : 0.f;
        float mf  = deg > 0 ? 1.f : 0.f;
        float Lx = mf*bflo(ux) - sx*inv;    // Lap feat 2pL
        float Ly = mf*bfhi(ux) - sy*inv;    // Lap feat 2pL+1

        // conv (no bias): out channels (2pL, 2pL+1), inputs = group-w feats via shfl
        float accx = 0.f, accy = 0.f;
        #pragma unroll
        for (int d = 0; d < 16; ++d) {
            int sl = w*16 + d;
            float ax = __shfl(Lx, sl);      // feat 32w+2d
            float ay = __shfl(Ly, sl);      // feat 32w+2d+1
            float2 wa = wc[(2*d)*16];       // W[w][2d][2jj..2jj+1]
            float2 wb = wc[(2*d+1)*16];
            accx = fmaf(ax, wa.x, accx); accx = fmaf(ay, wb.x, accx);
            accy = fmaf(ax, wa.y, accy); accy = fmaf(ay, wb.y, accy);
        }
        if (lane < 48) {
            float ox = fmaxf(accx + bflo(zu), 0.f);
            float oy = fmaxf(accy + bfhi(zu), 0.f);
            *(uintT*)(rb2 + (size_t)t*96 + 2*pL) = pack2(ox, oy);
        }
    }
}

// ---------- layer 3: out = widthmean(relu(Lap(rb2)@W_post + Zpost)) ----------
// persistent: 3125 blocks x 4 iters; weights staged once per block
__global__ __launch_bounds__(256) void lap3(
    const ushortT* __restrict__ Xb,    // rb2 [N+1,96]
    const ushortT* __restrict__ Pb,    // Zpost = cols 288..479
    const int* __restrict__ src, const int* __restrict__ row_ptr,
    const float2* __restrict__ Wp2,    // [3][16][64] float2
    float* __restrict__ out)
{
    __shared__ float2 wS[3*16*64];
    __shared__ float  sm[4][96];       // per-wave activation slab (wave DS in-order)
    for (int i = threadIdx.x; i < 3072; i += 256) wS[i] = Wp2[i];
    __syncthreads();

    int lane = threadIdx.x & 63;
    int wvw  = threadIdx.x >> 6;
    int pL = lane < 48 ? lane : 0;
    const float2* wl = wS + lane;      // step 64 float2 per (w,i2)

    #pragma unroll 1
    for (int it = 0; it < 4; ++it) {
        int t  = __builtin_amdgcn_readfirstlane(blockIdx.x*16 + it*4 + wvw);
        int lo = __builtin_amdgcn_readfirstlane(row_ptr[t]);
        int deg = __builtin_amdgcn_readfirstlane(row_ptr[t+1]) - lo;
        MAKE_SV(lo, deg, lane, 192, sv)
        uintT ux = *(const uintT*)(Xb + (size_t)t*96 + 2*pL);
        float z0 = bflo((uintT)Pb[(size_t)t*PCOLS + 288 + lane]);   // ch lane
        float z1 = bflo((uintT)Pb[(size_t)t*PCOLS + 352 + lane]);   // ch 64+lane
        float z2 = bflo((uintT)Pb[(size_t)t*PCOLS + 416 + lane]);   // ch 128+lane

        GATHER96(Xb, lo, deg, sv, pL, 192, sx, sy)

        float inv = deg > 0 ? 1.f/(float)deg : 0.f;
        float mf  = deg > 0 ? 1.f : 0.f;
        float Lx = mf*bflo(ux) - sx*inv;
        float Ly = mf*bfhi(ux) - sy*inv;

        // broadcast activations through per-wave LDS (uniform-address ds_read = broadcast)
        if (lane < 48) {
            sm[wvw][2*pL]     = Lx;
            sm[wvw][2*pL + 1] = Ly;
        }
        __builtin_amdgcn_wave_barrier();   // pin compiler order; wave DS ops are HW-in-order

        // conv: lane computes channels {L, 64+L, 128+L}
        float a0 = 0.f, a1 = 0.f, a2 = 0.f;
        #pragma unroll
        for (int w2 = 0; w2 < 3; ++w2) {
            float acc = 0.f;
            #pragma unroll
            for (int i2 = 0; i2 < 16; ++i2) {
                float2 iv = *(const float2*)(&sm[wvw][w2*32 + 2*i2]);   // broadcast read
                float2 p  = wl[(w2*16 + i2)*64];
                acc = fmaf(iv.x, p.x, acc);
                acc = fmaf(iv.y, p.y, acc);
            }
            if (w2 == 0) a0 = acc; else if (w2 == 1) a1 = acc; else a2 = acc;
        }
        __builtin_amdgcn_wave_barrier();   // reads done before next iter's sm writes

        float o0 = fmaxf(a0 + z0, 0.f);   // channel lane
        float o1 = fmaxf(a1 + z1, 0.f);   // channel 64+lane
        float o2 = fmaxf(a2 + z2, 0.f);   // channel 128+lane
        // width-mean: final[f] = (v(3f)+v(3f+1)+v(3f+2))/3, v(c) = o_{c>>6} @ lane c&63
        float r = 0.f;
        #pragma unroll
        for (int q = 0; q < 3; ++q) {
            int c = 3*lane + q;
            int sl = c & 63, wsel = c >> 6;
            float v0 = __shfl(o0, sl);
            float v1 = __shfl(o1, sl);
            float v2 = __shfl(o2, sl);
            r += (wsel == 0) ? v0 : ((wsel == 1) ? v1 : v2);
        }
        out[(size_t)t*64 + lane] = r * (1.0f/3.0f);
    }
}

extern "C" void kernel_launch(void* const* d_in, const int* in_sizes, int n_in,
                              void* d_out, int out_size, void* d_ws, size_t ws_size,
                              hipStream_t stream)
{
    const float* data    = (const float*)d_in[0];
    const int*   src     = (const int*)  d_in[1];
    const int*   tgt     = (const int*)  d_in[2];
    const float* W_pre   = (const float*)d_in[3];
    const float* b_pre   = (const float*)d_in[4];
    const float* T_pre   = (const float*)d_in[5];
    const float* bT_pre  = (const float*)d_in[6];
    const float* W_blk   = (const float*)d_in[7];
    const float* b_blk   = (const float*)d_in[8];   // cancels under Lap — unused
    const float* T_blk   = (const float*)d_in[9];
    const float* bT_blk  = (const float*)d_in[10];
    const float* W_post  = (const float*)d_in[11];
    const float* b_post  = (const float*)d_in[12];  // cancels under Lap — unused
    const float* T_post  = (const float*)d_in[13];
    const float* bT_post = (const float*)d_in[14];
    float* out = (float*)d_out;

    float*   ws      = (float*)d_ws;
    float*   bcat    = ws;                                   // 512 f32
    float2*  Wp2     = (float2*)(bcat + 512);                // 3*16*64 float2
    int*     row_ptr = (int*)(Wp2 + 3*16*64);                // 50008
    ushortT* Pb      = (ushortT*)(row_ptr + 50008);          // (N+1)*512 bf16
    ushortT* rb1     = Pb  + (size_t)(N_NODES+1) * PCOLS;    // (N+1)*96 bf16
    ushortT* rb2     = rb1 + (size_t)(N_NODES+1) * 96;       // (N+1)*96 bf16
    ushortT* Ab      = rb2 + (size_t)(N_NODES+1) * 96;       // N*128 bf16
    ushortT* Wb      = Ab  + (size_t)N_NODES * IN_F;         // 512*128 bf16

    prep1<<<(N_NODES*IN_F/8)/256, 256, 0, stream>>>(
        data, W_pre, b_pre, T_pre, bT_pre, T_blk, bT_blk, T_post, bT_post,
        W_post, tgt, Wb, bcat, Wp2, Ab, row_ptr, Pb, rb1, rb2);

    gemm_mfma<<<1568, 256, 0, stream>>>(Ab, Wb, bcat, Pb, N_NODES);

    lap1<<<N_NODES/4, 256, 0, stream>>>(Pb, src, row_ptr, rb1);
    lap2<<<N_NODES/16, 256, 0, stream>>>(rb1, Pb, src, row_ptr, W_blk, rb2);
    lap3<<<N_NODES/16, 256, 0, stream>>>(rb2, Pb, src, row_ptr, Wp2, out);
}

// Round 6
// 262.514 us; speedup vs baseline: 1.2184x; 1.0466x over previous
//
#include <hip/hip_runtime.h>
#include <hip/hip_fp8.h>
#include <cstdint>
#include <cstddef>

#define N_NODES 50000
#define E_EDGES 800000
#define IN_F    128
#define PCOLS   512   // Pb cols: [0,96) Y0 | [96,192) Zpre | [192,288) Zblk | [288,480) Zpost | pad

typedef unsigned short ushortT;
typedef unsigned int   uintT;
typedef unsigned char  u8T;
typedef __attribute__((ext_vector_type(8))) short s8v;   // 8 bf16 (4 VGPR)
typedef __attribute__((ext_vector_type(4))) float f4v;   // 4 fp32 acc
typedef __attribute__((ext_vector_type(2))) float f2v;   // packed fp32 pair

__device__ __forceinline__ float bflo(uintT u){ union{uintT i;float f;}c; c.i=u<<16; return c.f; }
__device__ __forceinline__ float bfhi(uintT u){ union{uintT i;float f;}c; c.i=u&0xFFFF0000u; return c.f; }
__device__ __forceinline__ ushortT f2bfu(float f){
    union{float f;uintT u;}c; c.f=f;
    uintT r = c.u + 0x7FFF + ((c.u>>16)&1);
    return (ushortT)(r>>16);
}
__device__ __forceinline__ uintT pack2(float a, float b){
    return (uintT)f2bfu(a) | ((uintT)f2bfu(b) << 16);
}
// fp8 e4m3 (OCP on gfx950) helpers — HW cvt via HIP type
__device__ __forceinline__ float f8f(uintT b){
    __hip_fp8_e4m3 h; h.__x = (__hip_fp8_storage_t)(b & 0xFF); return (float)h;
}
__device__ __forceinline__ uintT ff8(float f){
    __hip_fp8_e4m3 h(f); return (uintT)h.__x;
}

// ---------- prep1: pack weights + convert data + row_ptr + fp8 dummy rows ----------
// grid = 800000 threads exactly (N*IN_F/8)
__global__ void prep1(const float* __restrict__ A,
                      const float* __restrict__ Wp,  const float* __restrict__ bp,
                      const float* __restrict__ Tp,  const float* __restrict__ bTp,
                      const float* __restrict__ Tb,  const float* __restrict__ bTb,
                      const float* __restrict__ Tpo, const float* __restrict__ bTpo,
                      const float* __restrict__ Wpost,
                      const int* __restrict__ tgt,
                      ushortT* __restrict__ Wb, float* __restrict__ bcat,
                      float2* __restrict__ Wp2,
                      ushortT* __restrict__ Ab, int* __restrict__ row_ptr,
                      u8T* __restrict__ rb1f8, u8T* __restrict__ rb2f8)
{
    int gid = blockIdx.x * 256 + threadIdx.x;
    {
        size_t off = (size_t)gid * 8;
        float4 v0 = *(const float4*)(A + off);
        float4 v1 = *(const float4*)(A + off + 4);
        uint4 u;
        u.x = pack2(v0.x, v0.y); u.y = pack2(v0.z, v0.w);
        u.z = pack2(v1.x, v1.y); u.w = pack2(v1.z, v1.w);
        *(uint4*)(Ab + off) = u;
    }
    if (gid < IN_F * PCOLS) {
        int k = gid >> 9;
        int c = gid & 511;
        float v;
        if      (c < 96)  v = Wp [k*96  + c];
        else if (c < 192) v = Tp [k*96  + (c-96)];
        else if (c < 288) v = Tb [k*96  + (c-192)];
        else if (c < 480) v = Tpo[k*192 + (c-288)];
        else              v = 0.f;
        Wb[(size_t)c*IN_F + k] = f2bfu(v);
        if (k == 0) {
            float b;
            if      (c < 96)  b = bp  [c];
            else if (c < 192) b = bTp [c-96];
            else if (c < 288) b = bTb [c-192];
            else if (c < 480) b = bTpo[c-288];
            else              b = 0.f;
            bcat[c] = b;
        }
        if (gid < 3*16*64) {   // Wp2[(w*16+i2)*64+j] = (Wpost[w][2i2][j], Wpost[w][2i2+1][j])
            int w = gid >> 10, r = gid & 1023;
            int i2 = r >> 6, j = r & 63;
            Wp2[gid] = make_float2(Wpost[(w*32 + 2*i2)*64 + j],
                                   Wpost[(w*32 + 2*i2 + 1)*64 + j]);
        }
    }
    if (gid < 24) {   // fp8 dummy gather row (node N) = 0
        *(uintT*)(rb1f8 + (size_t)N_NODES*96 + 4*gid) = 0;
        *(uintT*)(rb2f8 + (size_t)N_NODES*96 + 4*gid) = 0;
    }
    if (gid <= N_NODES) {
        int lo = 0, hi = E_EDGES;
        while (lo < hi) {
            int mid = (lo + hi) >> 1;
            if (tgt[mid] < gid) lo = mid + 1; else hi = mid;
        }
        row_ptr[gid] = lo;
    }
}

// ---------- MFMA GEMM: Pb[M,512] = bf16(Ab[M,128] @ Wb^T + bcat) ----------
__global__ __launch_bounds__(256, 4) void gemm_mfma(const ushortT* __restrict__ Ab,
                                                    const ushortT* __restrict__ Wb,
                                                    const float* __restrict__ bcat,
                                                    ushortT* __restrict__ Pb, int M)
{
    __shared__ ushortT Bsl[128][136];   // 34816 B; B tile [n][k], reused as C staging
    int tid = threadIdx.x;
    int i = blockIdx.x;                  // 1568 = 8 * 49 * 4
    int xcd = i & 7, j = i >> 3;         // j in [0,196)
    int nb = (j & 3) * 128;              // column block
    int mb = (xcd * 49 + (j >> 2)) * 128;// row band (tail bands OOB-guarded)
    int wv = tid >> 6, lane = tid & 63;
    int wm = wv >> 1, wn = wv & 1;
    int cl = lane & 15, q = lane >> 4;

    #pragma unroll
    for (int r = 0; r < 8; ++r) {
        int idx = tid + 256*r;
        int row = idx >> 4, qq = idx & 15;
        uint4 v = *(const uint4*)(Wb + (size_t)(nb+row)*IN_F + qq*8);
        *(uint4*)(&Bsl[row][qq*8]) = v;
    }
    __syncthreads();

    f4v acc[4][4];
    #pragma unroll
    for (int a = 0; a < 4; ++a)
        #pragma unroll
        for (int b = 0; b < 4; ++b) acc[a][b] = (f4v)0.f;

    int gmBase = mb + wm*64;
    #pragma unroll
    for (int ks = 0; ks < 4; ++ks) {
        int ko = ks*32 + q*8;
        s8v af[4], bf[4];
        #pragma unroll
        for (int mt = 0; mt < 4; ++mt) {
            int gm = gmBase + mt*16 + cl;
            uint4 va = make_uint4(0,0,0,0);
            if (gm < M) va = *(const uint4*)(Ab + (size_t)gm*IN_F + ko);
            af[mt] = *(s8v*)&va;
        }
        #pragma unroll
        for (int nt = 0; nt < 4; ++nt)
            bf[nt] = *(const s8v*)(&Bsl[wn*64 + nt*16 + cl][ko]);
        #pragma unroll
        for (int mt = 0; mt < 4; ++mt)
            #pragma unroll
            for (int nt = 0; nt < 4; ++nt)
                acc[mt][nt] = __builtin_amdgcn_mfma_f32_16x16x32_bf16(af[mt], bf[nt], acc[mt][nt], 0, 0, 0);
    }

    __syncthreads();   // all waves done reading Bsl -> reuse as C staging

    #pragma unroll
    for (int nt = 0; nt < 4; ++nt) {
        int cn = wn*64 + nt*16 + cl;
        float bv = bcat[nb + cn];
        #pragma unroll
        for (int mt = 0; mt < 4; ++mt) {
            int rm0 = wm*64 + mt*16 + q*4;
            #pragma unroll
            for (int r = 0; r < 4; ++r)
                Bsl[rm0 + r][cn] = f2bfu(acc[mt][nt][r] + bv);
        }
    }
    __syncthreads();

    #pragma unroll
    for (int p = 0; p < 8; ++p) {
        int idx = tid + 256*p;
        int row = idx >> 4, sg = idx & 15;
        int gm = mb + row;
        if (gm < M) {
            uint4 v = *(const uint4*)(&Bsl[row][sg*8]);
            *(uint4*)(Pb + (size_t)gm*PCOLS + nb + sg*8) = v;
        }
    }
}

// ---------- cvt_y0: Y8[t][0..95] = fp8(Pb[t][0..95]) + zero dummy row ----------
// grid covers N*24 + 24 threads; thread -> 4 feats
__global__ void cvt_y0(const ushortT* __restrict__ Pb, u8T* __restrict__ Y8)
{
    int gid = blockIdx.x * 256 + threadIdx.x;
    if (gid < N_NODES*24) {
        int t = gid / 24, q = gid - t*24;
        uint2 rv = *(const uint2*)(Pb + (size_t)t*PCOLS + 4*q);
        uintT o = ff8(bflo(rv.x)) | (ff8(bfhi(rv.x)) << 8)
                | (ff8(bflo(rv.y)) << 16) | (ff8(bfhi(rv.y)) << 24);
        *(uintT*)(Y8 + (size_t)t*96 + 4*q) = o;
    } else if (gid < N_NODES*24 + 24) {
        *(uintT*)(Y8 + (size_t)N_NODES*96 + 4*(gid - N_NODES*24)) = 0;
    }
}

// ===== gather core (fp8 source): 16-deep windows; rows 96 B, 2B/lane loads =====
// sv holds PRE-SCALED byte offsets (row*96). Lane loads ushort (2 fp8 feats) at
// row + 2*pL; decode via HW cvt. 4 packed-f32 accumulators as before.
#define GATHER96F8(X8, lo, deg, sv, pL, sx, sy)                                   \
    float sx, sy;                                                                 \
    {                                                                             \
        f2v c0={0.f,0.f}, c1={0.f,0.f}, c2={0.f,0.f}, c3={0.f,0.f};               \
        int dmax = deg < 64 ? deg : 64;                                           \
        _Pragma("unroll 1")                                                       \
        for (int w_ = 0; w_ < dmax; w_ += 16) {                                   \
            uintT u[16];                                                          \
            _Pragma("unroll")                                                     \
            for (int kk = 0; kk < 16; ++kk) {                                     \
                int off = __builtin_amdgcn_readlane(sv, w_ + kk);                 \
                u[kk] = *(const ushortT*)((const u8T*)(X8) + off + 2*pL);         \
            }                                                                     \
            _Pragma("unroll")                                                     \
            for (int kk = 0; kk < 16; ++kk) {                                     \
                f2v v_; v_.x = f8f(u[kk]); v_.y = f8f(u[kk] >> 8);                \
                switch (kk & 3) {                                                 \
                    case 0: c0 += v_; break;                                      \
                    case 1: c1 += v_; break;                                      \
                    case 2: c2 += v_; break;                                      \
                    default:c3 += v_; break;                                      \
                }                                                                 \
            }                                                                     \
        }                                                                         \
        if (deg > 64) {                                                           \
            _Pragma("unroll 1")                                                   \
            for (int j_ = lo + 64; j_ < lo + deg; ++j_) {                         \
                int off = src[j_] * 96;                                           \
                uintT u0 = *(const ushortT*)((const u8T*)(X8) + off + 2*pL);      \
                f2v v_; v_.x = f8f(u0); v_.y = f8f(u0 >> 8);                      \
                c0 += v_;                                                         \
            }                                                                     \
        }                                                                         \
        f2v cs_ = (c0 + c1) + (c2 + c3);                                          \
        sx = cs_.x; sy = cs_.y;                                                   \
    }

// per-lane gather slot from raw src: lane<deg ? src[lo+lane]*96 : dummy row N
#define MAKE_SV96(lo, deg, lane, sv)                                              \
    int sv;                                                                       \
    {                                                                             \
        int e_ = (lo) + (lane);                                                   \
        if (e_ > E_EDGES - 1) e_ = E_EDGES - 1;                                   \
        int sn_ = src[e_];                                                        \
        sv = ((lane) < (deg) ? sn_ : N_NODES) * 96;                               \
    }

// ---------- layer 1: rb1 = bf16(relu(Lap(Y0) + Zpre)); gather from fp8 Y8 ----------
__global__ __launch_bounds__(256) void lap1(
    const ushortT* __restrict__ Pb,    // own-x (cols 0..95) + Zpre (96..191), bf16
    const u8T*     __restrict__ Y8,    // fp8 gather source [N+1,96]
    const int* __restrict__ src, const int* __restrict__ row_ptr,
    ushortT* __restrict__ rb1, u8T* __restrict__ rb1f8)
{
    int lane = threadIdx.x & 63;
    int t  = __builtin_amdgcn_readfirstlane((blockIdx.x << 2) + (threadIdx.x >> 6));
    int lo = __builtin_amdgcn_readfirstlane(row_ptr[t]);
    int deg = __builtin_amdgcn_readfirstlane(row_ptr[t+1]) - lo;
    int pL = lane < 48 ? lane : 0;
    MAKE_SV96(lo, deg, lane, sv)
    uintT ux = *(const uintT*)(Pb + (size_t)t*PCOLS + 2*pL);        // Y0 bf16
    uintT zu = *(const uintT*)(Pb + (size_t)t*PCOLS + 96 + 2*pL);   // Zpre

    GATHER96F8(Y8, lo, deg, sv, pL, sx, sy)

    float inv = deg > 0 ? 1.f/(float)deg : 0.f;
    float mf  = deg > 0 ? 1.f : 0.f;
    if (lane < 48) {
        float ox = fmaxf(mf*bflo(ux) - sx*inv + bflo(zu), 0.f);
        float oy = fmaxf(mf*bfhi(ux) - sy*inv + bfhi(zu), 0.f);
        *(uintT*)(rb1 + (size_t)t*96 + 2*pL) = pack2(ox, oy);
        *(ushortT*)(rb1f8 + (size_t)t*96 + 2*pL) = (ushortT)(ff8(ox) | (ff8(oy) << 8));
    }
}

// ---------- layer 2: rb2 = bf16(relu(Lap(rb1)@W_blk + Zblk)); gather fp8 ----------
__global__ __launch_bounds__(256) void lap2(
    const ushortT* __restrict__ Xb,    // rb1 bf16 (own-x)
    const u8T*     __restrict__ X8,    // rb1 fp8 (gather)
    const ushortT* __restrict__ Pb,    // Zblk = cols 192..287
    const int* __restrict__ src, const int* __restrict__ row_ptr,
    const float* __restrict__ Wblk,    // [3][32][32] flat
    ushortT* __restrict__ rb2, u8T* __restrict__ rb2f8)
{
    __shared__ float wS[3*32*32];
    for (int i = threadIdx.x; i < 3072; i += 256) wS[i] = Wblk[i];
    __syncthreads();

    int lane = threadIdx.x & 63;
    int wvw  = threadIdx.x >> 6;
    int pL = lane < 48 ? lane : 0;
    int w  = pL >> 4;            // group (uniform per 16-lane slab)
    int jj = pL & 15;            // out pair index within group
    const float2* wc = ((const float2*)wS) + (w*512 + jj);   // &W[w][0][2jj]

    #pragma unroll 1
    for (int it = 0; it < 4; ++it) {
        int t  = __builtin_amdgcn_readfirstlane(blockIdx.x*16 + it*4 + wvw);
        int lo = __builtin_amdgcn_readfirstlane(row_ptr[t]);
        int deg = __builtin_amdgcn_readfirstlane(row_ptr[t+1]) - lo;
        MAKE_SV96(lo, deg, lane, sv)
        uintT ux = *(const uintT*)(Xb + (size_t)t*96 + 2*pL);
        uintT zu = *(const uintT*)(Pb + (size_t)t*PCOLS + 192 + 2*pL);

        GATHER96F8(X8, lo, deg, sv, pL, sx, sy)

        float inv = deg > 0 ? 1.f/(float)deg : 0.f;
        float mf  = deg > 0 ? 1.f : 0.f;
        float Lx = mf*bflo(ux) - sx*inv;    // Lap feat 2pL
        float Ly = mf*bfhi(ux) - sy*inv;    // Lap feat 2pL+1

        // conv (no bias): out channels (2pL, 2pL+1), inputs = group-w feats via shfl
        float accx = 0.f, accy = 0.f;
        #pragma unroll
        for (int d = 0; d < 16; ++d) {
            int sl = w*16 + d;
            float ax = __shfl(Lx, sl);      // feat 32w+2d
            float ay = __shfl(Ly, sl);      // feat 32w+2d+1
            float2 wa = wc[(2*d)*16];       // W[w][2d][2jj..2jj+1]
            float2 wb = wc[(2*d+1)*16];
            accx = fmaf(ax, wa.x, accx); accx = fmaf(ay, wb.x, accx);
            accy = fmaf(ax, wa.y, accy); accy = fmaf(ay, wb.y, accy);
        }
        if (lane < 48) {
            float ox = fmaxf(accx + bflo(zu), 0.f);
            float oy = fmaxf(accy + bfhi(zu), 0.f);
            *(uintT*)(rb2 + (size_t)t*96 + 2*pL) = pack2(ox, oy);
            *(ushortT*)(rb2f8 + (size_t)t*96 + 2*pL) = (ushortT)(ff8(ox) | (ff8(oy) << 8));
        }
    }
}

// ---------- layer 3: out = widthmean(relu(Lap(rb2)@W_post + Zpost)); gather fp8 ----------
__global__ __launch_bounds__(256) void lap3(
    const ushortT* __restrict__ Xb,    // rb2 bf16 (own-x)
    const u8T*     __restrict__ X8,    // rb2 fp8 (gather)
    const ushortT* __restrict__ Pb,    // Zpost = cols 288..479
    const int* __restrict__ src, const int* __restrict__ row_ptr,
    const float2* __restrict__ Wp2,    // [3][16][64] float2
    float* __restrict__ out)
{
    __shared__ float2 wS[3*16*64];
    __shared__ float  sm[4][96];       // per-wave activation slab (wave DS in-order)
    for (int i = threadIdx.x; i < 3072; i += 256) wS[i] = Wp2[i];
    __syncthreads();

    int lane = threadIdx.x & 63;
    int wvw  = threadIdx.x >> 6;
    int pL = lane < 48 ? lane : 0;
    const float2* wl = wS + lane;      // step 64 float2 per (w,i2)

    #pragma unroll 1
    for (int it = 0; it < 4; ++it) {
        int t  = __builtin_amdgcn_readfirstlane(blockIdx.x*16 + it*4 + wvw);
        int lo = __builtin_amdgcn_readfirstlane(row_ptr[t]);
        int deg = __builtin_amdgcn_readfirstlane(row_ptr[t+1]) - lo;
        MAKE_SV96(lo, deg, lane, sv)
        uintT ux = *(const uintT*)(Xb + (size_t)t*96 + 2*pL);
        float z0 = bflo((uintT)Pb[(size_t)t*PCOLS + 288 + lane]);   // ch lane
        float z1 = bflo((uintT)Pb[(size_t)t*PCOLS + 352 + lane]);   // ch 64+lane
        float z2 = bflo((uintT)Pb[(size_t)t*PCOLS + 416 + lane]);   // ch 128+lane

        GATHER96F8(X8, lo, deg, sv, pL, sx, sy)

        float inv = deg > 0 ? 1.f/(float)deg : 0.f;
        float mf  = deg > 0 ? 1.f : 0.f;
        float Lx = mf*bflo(ux) - sx*inv;
        float Ly = mf*bfhi(ux) - sy*inv;

        // broadcast activations through per-wave LDS (uniform-address ds_read = broadcast)
        if (lane < 48) {
            sm[wvw][2*pL]     = Lx;
            sm[wvw][2*pL + 1] = Ly;
        }
        __builtin_amdgcn_wave_barrier();   // pin compiler order; wave DS ops are HW-in-order

        // conv: lane computes channels {L, 64+L, 128+L}
        float a0 = 0.f, a1 = 0.f, a2 = 0.f;
        #pragma unroll
        for (int w2 = 0; w2 < 3; ++w2) {
            float acc = 0.f;
            #pragma unroll
            for (int i2 = 0; i2 < 16; ++i2) {
                float2 iv = *(const float2*)(&sm[wvw][w2*32 + 2*i2]);   // broadcast read
                float2 p  = wl[(w2*16 + i2)*64];
                acc = fmaf(iv.x, p.x, acc);
                acc = fmaf(iv.y, p.y, acc);
            }
            if (w2 == 0) a0 = acc; else if (w2 == 1) a1 = acc; else a2 = acc;
        }
        __builtin_amdgcn_wave_barrier();   // reads done before next iter's sm writes

        float o0 = fmaxf(a0 + z0, 0.f);   // channel lane
        float o1 = fmaxf(a1 + z1, 0.f);   // channel 64+lane
        float o2 = fmaxf(a2 + z2, 0.f);   // channel 128+lane
        // width-mean: final[f] = (v(3f)+v(3f+1)+v(3f+2))/3, v(c) = o_{c>>6} @ lane c&63
        float r = 0.f;
        #pragma unroll
        for (int q = 0; q < 3; ++q) {
            int c = 3*lane + q;
            int sl = c & 63, wsel = c >> 6;
            float v0 = __shfl(o0, sl);
            float v1 = __shfl(o1, sl);
            float v2 = __shfl(o2, sl);
            r += (wsel == 0) ? v0 : ((wsel == 1) ? v1 : v2);
        }
        out[(size_t)t*64 + lane] = r * (1.0f/3.0f);
    }
}

extern "C" void kernel_launch(void* const* d_in, const int* in_sizes, int n_in,
                              void* d_out, int out_size, void* d_ws, size_t ws_size,
                              hipStream_t stream)
{
    const float* data    = (const float*)d_in[0];
    const int*   src     = (const int*)  d_in[1];
    const int*   tgt     = (const int*)  d_in[2];
    const float* W_pre   = (const float*)d_in[3];
    const float* b_pre   = (const float*)d_in[4];
    const float* T_pre   = (const float*)d_in[5];
    const float* bT_pre  = (const float*)d_in[6];
    const float* W_blk   = (const float*)d_in[7];
    const float* b_blk   = (const float*)d_in[8];   // cancels under Lap — unused
    const float* T_blk   = (const float*)d_in[9];
    const float* bT_blk  = (const float*)d_in[10];
    const float* W_post  = (const float*)d_in[11];
    const float* b_post  = (const float*)d_in[12];  // cancels under Lap — unused
    const float* T_post  = (const float*)d_in[13];
    const float* bT_post = (const float*)d_in[14];
    float* out = (float*)d_out;

    float*   ws      = (float*)d_ws;
    float*   bcat    = ws;                                   // 512 f32
    float2*  Wp2     = (float2*)(bcat + 512);                // 3*16*64 float2
    int*     row_ptr = (int*)(Wp2 + 3*16*64);                // 50008
    ushortT* Pb      = (ushortT*)(row_ptr + 50008);          // (N+1)*512 bf16
    ushortT* rb1     = Pb  + (size_t)(N_NODES+1) * PCOLS;    // (N+1)*96 bf16
    ushortT* rb2     = rb1 + (size_t)(N_NODES+1) * 96;       // (N+1)*96 bf16
    ushortT* Ab      = rb2 + (size_t)(N_NODES+1) * 96;       // N*128 bf16
    ushortT* Wb      = Ab  + (size_t)N_NODES * IN_F;         // 512*128 bf16
    u8T*     Y8      = (u8T*)(Wb + 512*IN_F);                // (N+1)*96 fp8
    u8T*     rb1f8   = Y8  + (size_t)(N_NODES+1) * 96;       // (N+1)*96 fp8
    u8T*     rb2f8   = rb1f8 + (size_t)(N_NODES+1) * 96;     // (N+1)*96 fp8

    prep1<<<(N_NODES*IN_F/8)/256, 256, 0, stream>>>(
        data, W_pre, b_pre, T_pre, bT_pre, T_blk, bT_blk, T_post, bT_post,
        W_post, tgt, Wb, bcat, Wp2, Ab, row_ptr, rb1f8, rb2f8);

    gemm_mfma<<<1568, 256, 0, stream>>>(Ab, Wb, bcat, Pb, N_NODES);

    cvt_y0<<<(N_NODES*24 + 24 + 255)/256, 256, 0, stream>>>(Pb, Y8);

    lap1<<<N_NODES/4, 256, 0, stream>>>(Pb, Y8, src, row_ptr, rb1, rb1f8);
    lap2<<<N_NODES/16, 256, 0, stream>>>(rb1, rb1f8, Pb, src, row_ptr, W_blk, rb2, rb2f8);
    lap3<<<N_NODES/16, 256, 0, stream>>>(rb2, rb2f8, Pb, src, row_ptr, Wp2, out);
}